// Round 14
// baseline (298.909 us; speedup 1.0000x reference)
//
#include <hip/hip_runtime.h>

typedef __attribute__((ext_vector_type(4))) float f32x4;
typedef __attribute__((ext_vector_type(4))) int   i32x4;
typedef __attribute__((ext_vector_type(8))) short bf16x8;
typedef __attribute__((ext_vector_type(4))) short s16x4;

#define HD 16
#define SQ 2048
#define DM 1024
#define DK 64
#define QSCALE 0.18033688011112042f   // 0.125 * log2(e)

__device__ __forceinline__ short f2bf(float f){
  union { float f; unsigned u; } c; c.f = f;
  unsigned r = (c.u + 0x7FFFu + ((c.u >> 16) & 1u)) >> 16;
  return (short)r;
}
__device__ __forceinline__ f32x4 mfma16(bf16x8 a, bf16x8 b, f32x4 c){
  return __builtin_amdgcn_mfma_f32_16x16x32_bf16(a, b, c, 0, 0, 0);
}
// async global->LDS, 16B per lane. dst must be wave-uniform; src is per-lane.
__device__ __forceinline__ void gload16(const void* g, void* l){
  __builtin_amdgcn_global_load_lds(
      (const __attribute__((address_space(1))) unsigned*)g,
      (__attribute__((address_space(3))) unsigned*)l, 16, 0, 0);
}

// ---------------- fused prep: cast + 4x weight transpose + rope table ----------------
__global__ void k_prep(const float* __restrict__ x, short* __restrict__ xb,
    const float* __restrict__ W0, const float* __restrict__ W1,
    const float* __restrict__ W2, const float* __restrict__ W3,
    short* __restrict__ T0, short* __restrict__ T1,
    short* __restrict__ T2, short* __restrict__ T3,
    float2* __restrict__ rope)
{
  __shared__ float t[32][33];
  const int bid = blockIdx.x, tid = threadIdx.x;
  if (bid < 4096) {
    int i = (bid * 256 + tid) * 4;
    f32x4 v = *(const f32x4*)(x + i);
    s16x4 o;
    o[0] = f2bf(v[0]); o[1] = f2bf(v[1]); o[2] = f2bf(v[2]); o[3] = f2bf(v[3]);
    *(s16x4*)(xb + i) = o;
  } else if (bid < 8192) {
    int rem = bid - 4096;
    int z = rem >> 10, rxy = rem & 1023;
    int bx = rxy & 31, by = rxy >> 5;
    const float* W = (z == 0) ? W0 : (z == 1) ? W1 : (z == 2) ? W2 : W3;
    short* Wt = (z == 0) ? T0 : (z == 1) ? T1 : (z == 2) ? T2 : T3;
    int kx = bx * 32, nx = by * 32;
    int lx = tid & 31, ly = tid >> 5;
#pragma unroll
    for (int i2 = 0; i2 < 32; i2 += 8)
      t[ly + i2][lx] = W[(size_t)(kx + ly + i2) * DM + nx + lx];
    __syncthreads();
#pragma unroll
    for (int i2 = 0; i2 < 32; i2 += 8)
      Wt[(size_t)(nx + ly + i2) * DM + kx + lx] = f2bf(t[lx][ly + i2]);
  } else {
    int i = (bid - 8192) * 256 + tid;   // SQ*32 entries
    int s = i >> 5, d2 = i & 31;
    float theta = powf(10000.0f, -(float)d2 / 32.0f);
    float ang = (float)s * theta;
    rope[i] = make_float2(cosf(ang), sinf(ang));
  }
}

// ---------------- fused QKV projection GEMM ----------------
__global__ __launch_bounds__(256) void k_projqkv(const short* __restrict__ A,
    const short* __restrict__ Wqt, const short* __restrict__ Wkt, const short* __restrict__ Wvt,
    const float* __restrict__ bq, const float* __restrict__ bk, const float* __restrict__ bv,
    const float2* __restrict__ rope,
    short* __restrict__ Qo, short* __restrict__ Ko, short* __restrict__ Vo)
{
  __shared__ short As[128 * 64];
  __shared__ short Bs[128 * 64];
  const int mat = blockIdx.y >> 3;
  const int n0 = (blockIdx.y & 7) * 128;
  const short* Bt  = (mat == 0) ? Wqt : (mat == 1) ? Wkt : Wvt;
  const float* bias = (mat == 0) ? bq : (mat == 1) ? bk : bv;
  const int tid = threadIdx.x;
  const int lane = tid & 63, w = tid >> 6;
  const int wr = w >> 1, wc = w & 1;
  const int l15 = lane & 15, l4 = lane >> 4;
  const int m0 = blockIdx.x * 128;
  f32x4 acc[4][4] = {};

  for (int k0 = 0; k0 < DM; k0 += 64) {
#pragma unroll
    for (int i = 0; i < 4; ++i) {
      int c = w * 4 + i;
      int row = c * 8 + (lane >> 3);
      int so = (((lane & 7) * 16) ^ ((row & 7) << 4)) >> 1;   // shorts, pre-swizzled
      gload16(A  + (size_t)(m0 + row) * DM + k0 + so, (char*)As + c * 1024);
      gload16(Bt + (size_t)(n0 + row) * DM + k0 + so, (char*)Bs + c * 1024);
    }
    __syncthreads();
#pragma unroll
    for (int kk = 0; kk < 64; kk += 32) {
      bf16x8 af[4], bfr[4];
#pragma unroll
      for (int mi = 0; mi < 4; ++mi) {
        int r = wr * 64 + mi * 16 + l15;
        af[mi] = *(const bf16x8*)((char*)As + ((r * 128 + kk * 2 + l4 * 16) ^ ((r & 7) << 4)));
      }
#pragma unroll
      for (int ni = 0; ni < 4; ++ni) {
        int r = wc * 64 + ni * 16 + l15;
        bfr[ni] = *(const bf16x8*)((char*)Bs + ((r * 128 + kk * 2 + l4 * 16) ^ ((r & 7) << 4)));
      }
#pragma unroll
      for (int mi = 0; mi < 4; ++mi)
#pragma unroll
        for (int ni = 0; ni < 4; ++ni)
          acc[mi][ni] = mfma16(af[mi], bfr[ni], acc[mi][ni]);
    }
    __syncthreads();
  }

#pragma unroll
  for (int mi = 0; mi < 4; ++mi) {
#pragma unroll
    for (int ni = 0; ni < 4; ++ni) {
      int n = n0 + wc * 64 + ni * 16 + l15;
      float bv2 = bias[n];
      if (mat == 2) {
        s16x4 pk;
        int mb = m0 + wr * 64 + mi * 16 + l4 * 4;
#pragma unroll
        for (int r2 = 0; r2 < 4; ++r2) pk[r2] = f2bf(acc[mi][ni][r2] + bv2);
        int b = mb >> 11, s = mb & 2047, h = n >> 6, d = n & 63;
        *(s16x4*)(Vo + ((size_t)((b * HD + h) * DK + d)) * SQ + s) = pk;
      } else {
        short* outp = (mat == 0) ? Qo : Ko;
        float sc = (mat == 0) ? QSCALE : 1.0f;
#pragma unroll
        for (int r2 = 0; r2 < 4; ++r2) {
          int m = m0 + wr * 64 + mi * 16 + l4 * 4 + r2;
          float v = acc[mi][ni][r2] + bv2;
          float pr = __shfl_xor(v, 1);
          int s = m & 2047, d = n & 63;
          float2 cs = rope[(s << 5) + (d >> 1)];
          v = (d & 1) ? (v * cs.x + pr * cs.y) : (v * cs.x - pr * cs.y);
          v *= sc;
          int b = m >> 11, h = n >> 6;
          outp[((size_t)((b * HD + h) * SQ + s)) * DK + d] = f2bf(v);
        }
      }
    }
  }
}

// ---------------- O projection: 64x128 tile, grid (64,8) ----------------
__global__ __launch_bounds__(256) void k_projO(const short* __restrict__ A, const short* __restrict__ Bt,
                                               const float* __restrict__ bias, float* __restrict__ out)
{
  __shared__ short As[64 * 64];
  __shared__ short Bs[128 * 64];
  const int tid = threadIdx.x;
  const int lane = tid & 63, w = tid >> 6;
  const int wr = w >> 1, wc = w & 1;
  const int l15 = lane & 15, l4 = lane >> 4;
  const int m0 = blockIdx.x * 64, n0 = blockIdx.y * 128;
  f32x4 acc[2][4] = {};

  for (int k0 = 0; k0 < DM; k0 += 64) {
#pragma unroll
    for (int i = 0; i < 2; ++i) {
      int c = w * 2 + i;
      int row = c * 8 + (lane >> 3);
      int so = (((lane & 7) * 16) ^ ((row & 7) << 4)) >> 1;
      gload16(A + (size_t)(m0 + row) * DM + k0 + so, (char*)As + c * 1024);
    }
#pragma unroll
    for (int i = 0; i < 4; ++i) {
      int c = w * 4 + i;
      int row = c * 8 + (lane >> 3);
      int so = (((lane & 7) * 16) ^ ((row & 7) << 4)) >> 1;
      gload16(Bt + (size_t)(n0 + row) * DM + k0 + so, (char*)Bs + c * 1024);
    }
    __syncthreads();
#pragma unroll
    for (int kk = 0; kk < 64; kk += 32) {
      bf16x8 af[2], bfr[4];
#pragma unroll
      for (int mi = 0; mi < 2; ++mi) {
        int r = wr * 32 + mi * 16 + l15;
        af[mi] = *(const bf16x8*)((char*)As + ((r * 128 + kk * 2 + l4 * 16) ^ ((r & 7) << 4)));
      }
#pragma unroll
      for (int ni = 0; ni < 4; ++ni) {
        int r = wc * 64 + ni * 16 + l15;
        bfr[ni] = *(const bf16x8*)((char*)Bs + ((r * 128 + kk * 2 + l4 * 16) ^ ((r & 7) << 4)));
      }
#pragma unroll
      for (int mi = 0; mi < 2; ++mi)
#pragma unroll
        for (int ni = 0; ni < 4; ++ni)
          acc[mi][ni] = mfma16(af[mi], bfr[ni], acc[mi][ni]);
    }
    __syncthreads();
  }

#pragma unroll
  for (int mi = 0; mi < 2; ++mi)
#pragma unroll
    for (int ni = 0; ni < 4; ++ni) {
      int n = n0 + wc * 64 + ni * 16 + l15;
      float bv2 = bias[n];
#pragma unroll
      for (int r2 = 0; r2 < 4; ++r2) {
        int m = m0 + wr * 32 + mi * 16 + l4 * 4 + r2;
        out[(size_t)m * DM + n] = acc[mi][ni][r2] + bv2;
      }
    }
}

// ---------------- fused attention (R10 base + dense sweep-1) ----------------
// Sweep 1: wave owns 16 keys x all 64 q -> 16 MFMA per 4 K-frag loads (4:1).
// Sweep 2: identical to R10 (2q x 2k split, K/V LDS dbuf, nt stores).
__global__ __launch_bounds__(256, 4) void k_attn2(const short* __restrict__ Q, const short* __restrict__ K,
    const short* __restrict__ Vt, float* __restrict__ attn_out, short* __restrict__ ctx)
{
  __shared__ short KV4[4][64 * 64];   // sweep1: 4-slot K ring; sweep2: [0,1]=K dbuf, [2,3]=V dbuf
  __shared__ short Ps[64 * 64];       // [64 q][64 keys], swz ((q&7)<<4); warp-private quadrants
  const int idx = blockIdx.x;
  const int xcd = idx & 7, g = idx >> 3;
  const int bh = xcd * 4 + (g >> 5);
  const int qt = g & 31;
  const int tid = threadIdx.x, lane = tid & 63, w = tid >> 6;
  const int l15 = lane & 15, l4 = lane >> 4;
  const int qg = w >> 1, kg = w & 1;
  const short* Qg = Q + (size_t)(bh * SQ + qt * 64) * DK;
  const short* Kg = K + (size_t)bh * SQ * DK;
  const short* Vg = Vt + (size_t)bh * DK * SQ;
  char* KVb = (char*)KV4;

  // staging geometry (per thread: 2 chunks of 16B per 64x64 tile)
  const int c0 = w * 2, c1 = w * 2 + 1;
  const int row0 = c0 * 8 + (lane >> 3), row1 = c1 * 8 + (lane >> 3);
  const int so0 = (((lane & 7) * 16) ^ ((row0 & 7) << 4)) >> 1;  // shorts, pre-swizzled
  const int so1 = (((lane & 7) * 16) ^ ((row1 & 7) << 4)) >> 1;

  // Q B-frags for ALL 64 q-rows (4 qs x 2 kx) -- sweep 2 uses the [qg*2+qs] subset
  bf16x8 q_b4[4][2];
#pragma unroll
  for (int qs = 0; qs < 4; ++qs)
#pragma unroll
    for (int kx = 0; kx < 2; ++kx)
      q_b4[qs][kx] = *(const bf16x8*)(Qg + (qs * 16 + l15) * 64 + kx * 32 + l4 * 8);

  // ---- sweep 1: dense rowsums; wave owns 16 keys per 64-key slot, all 64 q ----
  gload16(Kg + (size_t)row0 * 64 + so0, KVb + 0 * 8192 + c0 * 1024);
  gload16(Kg + (size_t)row1 * 64 + so1, KVb + 0 * 8192 + c1 * 1024);
  gload16(Kg + (size_t)(64 + row0) * 64 + so0, KVb + 1 * 8192 + c0 * 1024);
  gload16(Kg + (size_t)(64 + row1) * 64 + so1, KVb + 1 * 8192 + c1 * 1024);
  __syncthreads();
  float rs[4] = {0.0f, 0.0f, 0.0f, 0.0f};
  for (int i = 0; i < 16; ++i) {
    int cur = (i & 1) * 2;
    if (i < 15) {
      int nb = (i + 1) * 128, ns = cur ^ 2;
      gload16(Kg + (size_t)(nb + row0) * 64 + so0, KVb + ns * 8192 + c0 * 1024);
      gload16(Kg + (size_t)(nb + row1) * 64 + so1, KVb + ns * 8192 + c1 * 1024);
      gload16(Kg + (size_t)(nb + 64 + row0) * 64 + so0, KVb + (ns + 1) * 8192 + c0 * 1024);
      gload16(Kg + (size_t)(nb + 64 + row1) * 64 + so1, KVb + (ns + 1) * 8192 + c1 * 1024);
    }
#pragma unroll
    for (int sl = 0; sl < 2; ++sl) {
      const char* Kc = KVb + (cur + sl) * 8192;
      bf16x8 af[2];
#pragma unroll
      for (int kx = 0; kx < 2; ++kx) {
        int r = w * 16 + l15;
        af[kx] = *(const bf16x8*)(Kc + ((r * 128 + kx * 64 + l4 * 16) ^ ((r & 7) << 4)));
      }
#pragma unroll
      for (int qs = 0; qs < 4; ++qs) {
        f32x4 p = {};
        p = mfma16(af[0], q_b4[qs][0], p);
        p = mfma16(af[1], q_b4[qs][1], p);
#pragma unroll
        for (int r2 = 0; r2 < 4; ++r2) rs[qs] += exp2f(p[r2]);
      }
    }
    __syncthreads();
  }
  // within-wave: combine 4 l4-groups (disjoint keys, same q=qs*16+l15)
  float rinv0, rinv1;
  {
    float* rst = (float*)Ps;   // [64 q][4 w] = 256 floats
#pragma unroll
    for (int qs = 0; qs < 4; ++qs) {
      float v = rs[qs];
      v += __shfl_xor(v, 16);
      v += __shfl_xor(v, 32);
      if (lane < 16) rst[(qs * 16 + l15) * 4 + w] = v;
    }
    __syncthreads();
    // each thread needs rinv for sweep-2 rows q = qg*32 + qs2*16 + l15
    int q0 = qg * 32 + l15;
    rinv0 = 1.0f / (rst[q0 * 4 + 0] + rst[q0 * 4 + 1] + rst[q0 * 4 + 2] + rst[q0 * 4 + 3]);
    int q1 = qg * 32 + 16 + l15;
    rinv1 = 1.0f / (rst[q1 * 4 + 0] + rst[q1 * 4 + 1] + rst[q1 * 4 + 2] + rst[q1 * 4 + 3]);
  }

  // ---- sweep 2: recompute (R10-identical), nt f32 weight stores, PV ----
  f32x4 c[2][4] = {};
  float* attn_base = attn_out + ((size_t)(bh * SQ + qt * 64)) * SQ;

  gload16(Kg + (size_t)row0 * 64 + so0, KVb + 0 * 8192 + c0 * 1024);
  gload16(Kg + (size_t)row1 * 64 + so1, KVb + 0 * 8192 + c1 * 1024);
  gload16(Vg + (size_t)row0 * SQ + so0, KVb + 2 * 8192 + c0 * 1024);
  gload16(Vg + (size_t)row1 * SQ + so1, KVb + 2 * 8192 + c1 * 1024);
  __syncthreads();
  for (int t = 0; t < 32; ++t) {
    int cur = t & 1;
    if (t < 31) {
      gload16(Kg + (size_t)((t + 1) * 64 + row0) * 64 + so0, KVb + (cur ^ 1) * 8192 + c0 * 1024);
      gload16(Kg + (size_t)((t + 1) * 64 + row1) * 64 + so1, KVb + (cur ^ 1) * 8192 + c1 * 1024);
      gload16(Vg + (size_t)row0 * SQ + (t + 1) * 64 + so0, KVb + (2 + (cur ^ 1)) * 8192 + c0 * 1024);
      gload16(Vg + (size_t)row1 * SQ + (t + 1) * 64 + so1, KVb + (2 + (cur ^ 1)) * 8192 + c1 * 1024);
    }
    const char* Kc = KVb + cur * 8192;
    const char* Vc = KVb + (2 + cur) * 8192;
    bf16x8 af[2][2];
#pragma unroll
    for (int ks = 0; ks < 2; ++ks)
#pragma unroll
      for (int kx = 0; kx < 2; ++kx) {
        int r = kg * 32 + ks * 16 + l15;
        af[ks][kx] = *(const bf16x8*)(Kc + ((r * 128 + kx * 64 + l4 * 16) ^ ((r & 7) << 4)));
      }
#pragma unroll
    for (int qs = 0; qs < 2; ++qs) {
      const float rinv = qs ? rinv1 : rinv0;
#pragma unroll
      for (int ks = 0; ks < 2; ++ks) {
        f32x4 p = {};
        p = mfma16(af[ks][0], q_b4[qg * 2 + qs][0], p);
        p = mfma16(af[ks][1], q_b4[qg * 2 + qs][1], p);
        f32x4 wv;
        s16x4 pk;
#pragma unroll
        for (int r2 = 0; r2 < 4; ++r2) {
          wv[r2] = exp2f(p[r2]) * rinv;
          pk[r2] = f2bf(wv[r2]);
        }
        int qr = qg * 32 + qs * 16 + l15;
        __builtin_nontemporal_store(wv,
            (f32x4*)(attn_base + (size_t)qr * SQ + t * 64 + kg * 32 + ks * 16 + l4 * 4));
        *(s16x4*)((char*)Ps + ((qr * 128 + kg * 64 + ks * 32 + l4 * 8) ^ ((qr & 7) << 4))) = pk;
      }
    }
    // PV over warp's own 32 keys (quadrant warp-private; no barrier needed)
#pragma unroll
    for (int qs = 0; qs < 2; ++qs) {
      int qr = qg * 32 + qs * 16 + l15;
      bf16x8 ap = *(const bf16x8*)((char*)Ps + ((qr * 128 + kg * 64 + l4 * 16) ^ ((qr & 7) << 4)));
#pragma unroll
      for (int ds = 0; ds < 4; ++ds) {
        int r = ds * 16 + l15;
        bf16x8 bv = *(const bf16x8*)(Vc + ((r * 128 + kg * 64 + l4 * 16) ^ ((r & 7) << 4)));
        c[qs][ds] = mfma16(ap, bv, c[qs][ds]);
      }
    }
    __syncthreads();
  }
  // cross-warp (kg) reduction of PV partials via retired KV4 (f32 [64][64])
  float* red = (float*)KV4;
  if (kg == 1) {
#pragma unroll
    for (int qs = 0; qs < 2; ++qs)
#pragma unroll
      for (int ds = 0; ds < 4; ++ds)
#pragma unroll
        for (int r2 = 0; r2 < 4; ++r2)
          red[(qg * 32 + qs * 16 + l4 * 4 + r2) * 64 + ds * 16 + l15] = c[qs][ds][r2];
  }
  __syncthreads();
  if (kg == 0) {
    int b = bh >> 4, h = bh & 15;
#pragma unroll
    for (int qs = 0; qs < 2; ++qs)
#pragma unroll
      for (int ds = 0; ds < 4; ++ds)
#pragma unroll
        for (int r2 = 0; r2 < 4; ++r2) {
          int qr = qg * 32 + qs * 16 + l4 * 4 + r2;
          float v = c[qs][ds][r2] + red[qr * 64 + ds * 16 + l15];
          int s = qt * 64 + qr, d = ds * 16 + l15;
          ctx[((size_t)(b * SQ + s)) * DM + h * DK + d] = f2bf(v);
        }
  }
}

extern "C" void kernel_launch(void* const* d_in, const int* in_sizes, int n_in,
                              void* d_out, int out_size, void* d_ws, size_t ws_size,
                              hipStream_t stream)
{
  const float* x  = (const float*)d_in[0];
  const float* Wq = (const float*)d_in[1];
  const float* bq = (const float*)d_in[2];
  const float* Wk = (const float*)d_in[3];
  const float* bk = (const float*)d_in[4];
  const float* Wv = (const float*)d_in[5];
  const float* bv = (const float*)d_in[6];
  const float* Wo = (const float*)d_in[7];
  const float* bo = (const float*)d_in[8];

  char* p = (char*)d_ws;
  float2* rope = (float2*)p;  p += (size_t)SQ * 32 * sizeof(float2);
  short* xb  = (short*)p;     p += (size_t)4096 * DM * 2;
  short* Wqt = (short*)p;     p += (size_t)DM * DM * 2;
  short* Wkt = (short*)p;     p += (size_t)DM * DM * 2;
  short* Wvt = (short*)p;     p += (size_t)DM * DM * 2;
  short* Wot = (short*)p;     p += (size_t)DM * DM * 2;
  short* Qr  = (short*)p;     p += (size_t)2 * HD * SQ * DK * 2;
  short* Kr  = (short*)p;     p += (size_t)2 * HD * SQ * DK * 2;
  short* Vtr = (short*)p;     p += (size_t)2 * HD * SQ * DK * 2;
  short* ctx = (short*)p;     p += (size_t)4096 * DM * 2;

  k_prep<<<8448, 256, 0, stream>>>(x, xb, Wq, Wk, Wv, Wo, Wqt, Wkt, Wvt, Wot, rope);
  k_projqkv<<<dim3(32, 24), 256, 0, stream>>>(xb, Wqt, Wkt, Wvt, bq, bk, bv, rope, Qr, Kr, Vtr);
  float* attn = (float*)d_out + (size_t)2 * SQ * DM;
  k_attn2<<<1024, 256, 0, stream>>>(Qr, Kr, Vtr, attn, ctx);
  k_projO<<<dim3(64, 8), 256, 0, stream>>>(ctx, Wot, bo, (float*)d_out);
}

// Round 15
// 261.970 us; speedup vs baseline: 1.1410x; 1.1410x over previous
//
#include <hip/hip_runtime.h>

typedef __attribute__((ext_vector_type(4))) float f32x4;
typedef __attribute__((ext_vector_type(4))) int   i32x4;
typedef __attribute__((ext_vector_type(8))) short bf16x8;
typedef __attribute__((ext_vector_type(4))) short s16x4;

#define HD 16
#define SQ 2048
#define DM 1024
#define DK 64
#define QSCALE 0.18033688011112042f   // 0.125 * log2(e)

__device__ __forceinline__ short f2bf(float f){
  union { float f; unsigned u; } c; c.f = f;
  unsigned r = (c.u + 0x7FFFu + ((c.u >> 16) & 1u)) >> 16;
  return (short)r;
}
__device__ __forceinline__ f32x4 mfma16(bf16x8 a, bf16x8 b, f32x4 c){
  return __builtin_amdgcn_mfma_f32_16x16x32_bf16(a, b, c, 0, 0, 0);
}
// async global->LDS, 16B per lane. dst must be wave-uniform; src is per-lane.
__device__ __forceinline__ void gload16(const void* g, void* l){
  __builtin_amdgcn_global_load_lds(
      (const __attribute__((address_space(1))) unsigned*)g,
      (__attribute__((address_space(3))) unsigned*)l, 16, 0, 0);
}

// ---------------- fused prep: cast + 4x weight transpose + rope table ----------------
__global__ void k_prep(const float* __restrict__ x, short* __restrict__ xb,
    const float* __restrict__ W0, const float* __restrict__ W1,
    const float* __restrict__ W2, const float* __restrict__ W3,
    short* __restrict__ T0, short* __restrict__ T1,
    short* __restrict__ T2, short* __restrict__ T3,
    float2* __restrict__ rope)
{
  __shared__ float t[32][33];
  const int bid = blockIdx.x, tid = threadIdx.x;
  if (bid < 4096) {
    int i = (bid * 256 + tid) * 4;
    f32x4 v = *(const f32x4*)(x + i);
    s16x4 o;
    o[0] = f2bf(v[0]); o[1] = f2bf(v[1]); o[2] = f2bf(v[2]); o[3] = f2bf(v[3]);
    *(s16x4*)(xb + i) = o;
  } else if (bid < 8192) {
    int rem = bid - 4096;
    int z = rem >> 10, rxy = rem & 1023;
    int bx = rxy & 31, by = rxy >> 5;
    const float* W = (z == 0) ? W0 : (z == 1) ? W1 : (z == 2) ? W2 : W3;
    short* Wt = (z == 0) ? T0 : (z == 1) ? T1 : (z == 2) ? T2 : T3;
    int kx = bx * 32, nx = by * 32;
    int lx = tid & 31, ly = tid >> 5;
#pragma unroll
    for (int i2 = 0; i2 < 32; i2 += 8)
      t[ly + i2][lx] = W[(size_t)(kx + ly + i2) * DM + nx + lx];
    __syncthreads();
#pragma unroll
    for (int i2 = 0; i2 < 32; i2 += 8)
      Wt[(size_t)(nx + ly + i2) * DM + kx + lx] = f2bf(t[lx][ly + i2]);
  } else {
    int i = (bid - 8192) * 256 + tid;   // SQ*32 entries
    int s = i >> 5, d2 = i & 31;
    float theta = powf(10000.0f, -(float)d2 / 32.0f);
    float ang = (float)s * theta;
    rope[i] = make_float2(cosf(ang), sinf(ang));
  }
}

// ---------------- fused QKV projection GEMM ----------------
__global__ __launch_bounds__(256) void k_projqkv(const short* __restrict__ A,
    const short* __restrict__ Wqt, const short* __restrict__ Wkt, const short* __restrict__ Wvt,
    const float* __restrict__ bq, const float* __restrict__ bk, const float* __restrict__ bv,
    const float2* __restrict__ rope,
    short* __restrict__ Qo, short* __restrict__ Ko, short* __restrict__ Vo)
{
  __shared__ short As[128 * 64];
  __shared__ short Bs[128 * 64];
  const int mat = blockIdx.y >> 3;
  const int n0 = (blockIdx.y & 7) * 128;
  const short* Bt  = (mat == 0) ? Wqt : (mat == 1) ? Wkt : Wvt;
  const float* bias = (mat == 0) ? bq : (mat == 1) ? bk : bv;
  const int tid = threadIdx.x;
  const int lane = tid & 63, w = tid >> 6;
  const int wr = w >> 1, wc = w & 1;
  const int l15 = lane & 15, l4 = lane >> 4;
  const int m0 = blockIdx.x * 128;
  f32x4 acc[4][4] = {};

  for (int k0 = 0; k0 < DM; k0 += 64) {
#pragma unroll
    for (int i = 0; i < 4; ++i) {
      int c = w * 4 + i;
      int row = c * 8 + (lane >> 3);
      int so = (((lane & 7) * 16) ^ ((row & 7) << 4)) >> 1;   // shorts, pre-swizzled
      gload16(A  + (size_t)(m0 + row) * DM + k0 + so, (char*)As + c * 1024);
      gload16(Bt + (size_t)(n0 + row) * DM + k0 + so, (char*)Bs + c * 1024);
    }
    __syncthreads();
#pragma unroll
    for (int kk = 0; kk < 64; kk += 32) {
      bf16x8 af[4], bfr[4];
#pragma unroll
      for (int mi = 0; mi < 4; ++mi) {
        int r = wr * 64 + mi * 16 + l15;
        af[mi] = *(const bf16x8*)((char*)As + ((r * 128 + kk * 2 + l4 * 16) ^ ((r & 7) << 4)));
      }
#pragma unroll
      for (int ni = 0; ni < 4; ++ni) {
        int r = wc * 64 + ni * 16 + l15;
        bfr[ni] = *(const bf16x8*)((char*)Bs + ((r * 128 + kk * 2 + l4 * 16) ^ ((r & 7) << 4)));
      }
#pragma unroll
      for (int mi = 0; mi < 4; ++mi)
#pragma unroll
        for (int ni = 0; ni < 4; ++ni)
          acc[mi][ni] = mfma16(af[mi], bfr[ni], acc[mi][ni]);
    }
    __syncthreads();
  }

#pragma unroll
  for (int mi = 0; mi < 4; ++mi) {
#pragma unroll
    for (int ni = 0; ni < 4; ++ni) {
      int n = n0 + wc * 64 + ni * 16 + l15;
      float bv2 = bias[n];
      if (mat == 2) {
        s16x4 pk;
        int mb = m0 + wr * 64 + mi * 16 + l4 * 4;
#pragma unroll
        for (int r2 = 0; r2 < 4; ++r2) pk[r2] = f2bf(acc[mi][ni][r2] + bv2);
        int b = mb >> 11, s = mb & 2047, h = n >> 6, d = n & 63;
        *(s16x4*)(Vo + ((size_t)((b * HD + h) * DK + d)) * SQ + s) = pk;
      } else {
        short* outp = (mat == 0) ? Qo : Ko;
        float sc = (mat == 0) ? QSCALE : 1.0f;
#pragma unroll
        for (int r2 = 0; r2 < 4; ++r2) {
          int m = m0 + wr * 64 + mi * 16 + l4 * 4 + r2;
          float v = acc[mi][ni][r2] + bv2;
          float pr = __shfl_xor(v, 1);
          int s = m & 2047, d = n & 63;
          float2 cs = rope[(s << 5) + (d >> 1)];
          v = (d & 1) ? (v * cs.x + pr * cs.y) : (v * cs.x - pr * cs.y);
          v *= sc;
          int b = m >> 11, h = n >> 6;
          outp[((size_t)((b * HD + h) * SQ + s)) * DK + d] = f2bf(v);
        }
      }
    }
  }
}

// ---------------- O projection: 64x128 tile, grid (64,8) ----------------
__global__ __launch_bounds__(256) void k_projO(const short* __restrict__ A, const short* __restrict__ Bt,
                                               const float* __restrict__ bias, float* __restrict__ out)
{
  __shared__ short As[64 * 64];
  __shared__ short Bs[128 * 64];
  const int tid = threadIdx.x;
  const int lane = tid & 63, w = tid >> 6;
  const int wr = w >> 1, wc = w & 1;
  const int l15 = lane & 15, l4 = lane >> 4;
  const int m0 = blockIdx.x * 64, n0 = blockIdx.y * 128;
  f32x4 acc[2][4] = {};

  for (int k0 = 0; k0 < DM; k0 += 64) {
#pragma unroll
    for (int i = 0; i < 2; ++i) {
      int c = w * 2 + i;
      int row = c * 8 + (lane >> 3);
      int so = (((lane & 7) * 16) ^ ((row & 7) << 4)) >> 1;
      gload16(A + (size_t)(m0 + row) * DM + k0 + so, (char*)As + c * 1024);
    }
#pragma unroll
    for (int i = 0; i < 4; ++i) {
      int c = w * 4 + i;
      int row = c * 8 + (lane >> 3);
      int so = (((lane & 7) * 16) ^ ((row & 7) << 4)) >> 1;
      gload16(Bt + (size_t)(n0 + row) * DM + k0 + so, (char*)Bs + c * 1024);
    }
    __syncthreads();
#pragma unroll
    for (int kk = 0; kk < 64; kk += 32) {
      bf16x8 af[2], bfr[4];
#pragma unroll
      for (int mi = 0; mi < 2; ++mi) {
        int r = wr * 32 + mi * 16 + l15;
        af[mi] = *(const bf16x8*)((char*)As + ((r * 128 + kk * 2 + l4 * 16) ^ ((r & 7) << 4)));
      }
#pragma unroll
      for (int ni = 0; ni < 4; ++ni) {
        int r = wc * 64 + ni * 16 + l15;
        bfr[ni] = *(const bf16x8*)((char*)Bs + ((r * 128 + kk * 2 + l4 * 16) ^ ((r & 7) << 4)));
      }
#pragma unroll
      for (int mi = 0; mi < 2; ++mi)
#pragma unroll
        for (int ni = 0; ni < 4; ++ni)
          acc[mi][ni] = mfma16(af[mi], bfr[ni], acc[mi][ni]);
    }
    __syncthreads();
  }

#pragma unroll
  for (int mi = 0; mi < 2; ++mi)
#pragma unroll
    for (int ni = 0; ni < 4; ++ni) {
      int n = n0 + wc * 64 + ni * 16 + l15;
      float bv2 = bias[n];
#pragma unroll
      for (int r2 = 0; r2 < 4; ++r2) {
        int m = m0 + wr * 32 + mi * 16 + l4 * 4 + r2;
        out[(size_t)m * DM + n] = acc[mi][ni][r2] + bv2;
      }
    }
}

// ---------------- fused attention (R8 structure + sweep1 ring + nt stores) ----------------
// 2q x 2k warp split; K/V dbuf gload16 staging; Ps single buffer, warp-private quadrants.
// Sweep 1: 128 keys/iter via 4-slot ring (16 barriers). Sweep 2: as R8 but weight
// stores are NONTEMPORAL so the 536MB stream doesn't evict K/V from L2.
__global__ __launch_bounds__(256, 4) void k_attn2(const short* __restrict__ Q, const short* __restrict__ K,
    const short* __restrict__ Vt, float* __restrict__ attn_out, short* __restrict__ ctx)
{
  __shared__ short KV4[4][64 * 64];   // sweep1: 4-slot K ring; sweep2: [0,1]=K dbuf, [2,3]=V dbuf
  __shared__ short Ps[64 * 64];       // [64 q][64 keys], swz ((q&7)<<4); warp-private quadrants
  const int idx = blockIdx.x;
  const int xcd = idx & 7, g = idx >> 3;
  const int bh = xcd * 4 + (g >> 5);
  const int qt = g & 31;
  const int tid = threadIdx.x, lane = tid & 63, w = tid >> 6;
  const int l15 = lane & 15, l4 = lane >> 4;
  const int qg = w >> 1, kg = w & 1;
  const short* Qg = Q + (size_t)(bh * SQ + qt * 64) * DK;
  const short* Kg = K + (size_t)bh * SQ * DK;
  const short* Vg = Vt + (size_t)bh * DK * SQ;
  char* KVb = (char*)KV4;

  // staging geometry (per thread: 2 chunks of 16B per 64x64 tile)
  const int c0 = w * 2, c1 = w * 2 + 1;
  const int row0 = c0 * 8 + (lane >> 3), row1 = c1 * 8 + (lane >> 3);
  const int so0 = (((lane & 7) * 16) ^ ((row0 & 7) << 4)) >> 1;  // shorts, pre-swizzled
  const int so1 = (((lane & 7) * 16) ^ ((row1 & 7) << 4)) >> 1;

  // Q B-frags for this warp's 32 q-rows (2 qsub x 2 kx), registers
  bf16x8 q_b[2][2];
#pragma unroll
  for (int qs = 0; qs < 2; ++qs)
#pragma unroll
    for (int kx = 0; kx < 2; ++kx)
      q_b[qs][kx] = *(const bf16x8*)(Qg + (qg * 32 + qs * 16 + l15) * 64 + kx * 32 + l4 * 8);

  // ---- sweep 1: partial rowsums; 128 keys/iter via 4-slot K ring ----
  gload16(Kg + (size_t)row0 * 64 + so0, KVb + 0 * 8192 + c0 * 1024);
  gload16(Kg + (size_t)row1 * 64 + so1, KVb + 0 * 8192 + c1 * 1024);
  gload16(Kg + (size_t)(64 + row0) * 64 + so0, KVb + 1 * 8192 + c0 * 1024);
  gload16(Kg + (size_t)(64 + row1) * 64 + so1, KVb + 1 * 8192 + c1 * 1024);
  __syncthreads();
  float rs[2] = {0.0f, 0.0f};
  for (int i = 0; i < 16; ++i) {
    int cur = (i & 1) * 2;
    if (i < 15) {
      int nb = (i + 1) * 128, ns = cur ^ 2;
      gload16(Kg + (size_t)(nb + row0) * 64 + so0, KVb + ns * 8192 + c0 * 1024);
      gload16(Kg + (size_t)(nb + row1) * 64 + so1, KVb + ns * 8192 + c1 * 1024);
      gload16(Kg + (size_t)(nb + 64 + row0) * 64 + so0, KVb + (ns + 1) * 8192 + c0 * 1024);
      gload16(Kg + (size_t)(nb + 64 + row1) * 64 + so1, KVb + (ns + 1) * 8192 + c1 * 1024);
    }
#pragma unroll
    for (int sl = 0; sl < 2; ++sl) {
      const char* Kc = KVb + (cur + sl) * 8192;
      bf16x8 af[2][2];
#pragma unroll
      for (int ks = 0; ks < 2; ++ks)
#pragma unroll
        for (int kx = 0; kx < 2; ++kx) {
          int r = kg * 32 + ks * 16 + l15;
          af[ks][kx] = *(const bf16x8*)(Kc + ((r * 128 + kx * 64 + l4 * 16) ^ ((r & 7) << 4)));
        }
#pragma unroll
      for (int qs = 0; qs < 2; ++qs)
#pragma unroll
        for (int ks = 0; ks < 2; ++ks) {
          f32x4 p = {};
          p = mfma16(af[ks][0], q_b[qs][0], p);
          p = mfma16(af[ks][1], q_b[qs][1], p);
#pragma unroll
          for (int r2 = 0; r2 < 4; ++r2) rs[qs] += exp2f(p[r2]);
        }
    }
    __syncthreads();
  }
  // within-warp: combine 4 l4-groups (disjoint key subsets, same q=l15)
  float rv[2];
#pragma unroll
  for (int qs = 0; qs < 2; ++qs) {
    float v = rs[qs];
    v += __shfl_xor(v, 16);
    v += __shfl_xor(v, 32);
    rv[qs] = v;
  }
  // cross-warp (kg) combine via small LDS table in Ps area
  {
    float* rst = (float*)Ps;   // [2 qg][2 qs][16 q][2 kg] = 128 floats
    if (lane < 16) {
#pragma unroll
      for (int qs = 0; qs < 2; ++qs)
        rst[(((qg * 2 + qs) * 16 + l15) * 2) + kg] = rv[qs];
    }
    __syncthreads();
#pragma unroll
    for (int qs = 0; qs < 2; ++qs)
      rv[qs] = 1.0f / (rv[qs] + rst[(((qg * 2 + qs) * 16 + l15) * 2) + (kg ^ 1)]);
  }
  const float rinv0 = rv[0], rinv1 = rv[1];

  // ---- sweep 2: recompute (identical op order), nt f32 weight stores, PV ----
  f32x4 c[2][4] = {};
  float* attn_base = attn_out + ((size_t)(bh * SQ + qt * 64)) * SQ;

  gload16(Kg + (size_t)row0 * 64 + so0, KVb + 0 * 8192 + c0 * 1024);
  gload16(Kg + (size_t)row1 * 64 + so1, KVb + 0 * 8192 + c1 * 1024);
  gload16(Vg + (size_t)row0 * SQ + so0, KVb + 2 * 8192 + c0 * 1024);
  gload16(Vg + (size_t)row1 * SQ + so1, KVb + 2 * 8192 + c1 * 1024);
  __syncthreads();
  for (int t = 0; t < 32; ++t) {
    int cur = t & 1;
    if (t < 31) {
      gload16(Kg + (size_t)((t + 1) * 64 + row0) * 64 + so0, KVb + (cur ^ 1) * 8192 + c0 * 1024);
      gload16(Kg + (size_t)((t + 1) * 64 + row1) * 64 + so1, KVb + (cur ^ 1) * 8192 + c1 * 1024);
      gload16(Vg + (size_t)row0 * SQ + (t + 1) * 64 + so0, KVb + (2 + (cur ^ 1)) * 8192 + c0 * 1024);
      gload16(Vg + (size_t)row1 * SQ + (t + 1) * 64 + so1, KVb + (2 + (cur ^ 1)) * 8192 + c1 * 1024);
    }
    const char* Kc = KVb + cur * 8192;
    const char* Vc = KVb + (2 + cur) * 8192;
    bf16x8 af[2][2];
#pragma unroll
    for (int ks = 0; ks < 2; ++ks)
#pragma unroll
      for (int kx = 0; kx < 2; ++kx) {
        int r = kg * 32 + ks * 16 + l15;
        af[ks][kx] = *(const bf16x8*)(Kc + ((r * 128 + kx * 64 + l4 * 16) ^ ((r & 7) << 4)));
      }
#pragma unroll
    for (int qs = 0; qs < 2; ++qs) {
      const float rinv = qs ? rinv1 : rinv0;
#pragma unroll
      for (int ks = 0; ks < 2; ++ks) {
        f32x4 p = {};
        p = mfma16(af[ks][0], q_b[qs][0], p);
        p = mfma16(af[ks][1], q_b[qs][1], p);
        f32x4 wv;
        s16x4 pk;
#pragma unroll
        for (int r2 = 0; r2 < 4; ++r2) {
          wv[r2] = exp2f(p[r2]) * rinv;
          pk[r2] = f2bf(wv[r2]);
        }
        int qr = qg * 32 + qs * 16 + l15;
        __builtin_nontemporal_store(wv,
            (f32x4*)(attn_base + (size_t)qr * SQ + t * 64 + kg * 32 + ks * 16 + l4 * 4));
        *(s16x4*)((char*)Ps + ((qr * 128 + kg * 64 + ks * 32 + l4 * 8) ^ ((qr & 7) << 4))) = pk;
      }
    }
    // PV over warp's own 32 keys (quadrant warp-private; no barrier needed)
#pragma unroll
    for (int qs = 0; qs < 2; ++qs) {
      int qr = qg * 32 + qs * 16 + l15;
      bf16x8 ap = *(const bf16x8*)((char*)Ps + ((qr * 128 + kg * 64 + l4 * 16) ^ ((qr & 7) << 4)));
#pragma unroll
      for (int ds = 0; ds < 4; ++ds) {
        int r = ds * 16 + l15;
        bf16x8 bv = *(const bf16x8*)(Vc + ((r * 128 + kg * 64 + l4 * 16) ^ ((r & 7) << 4)));
        c[qs][ds] = mfma16(ap, bv, c[qs][ds]);
      }
    }
    __syncthreads();
  }
  // cross-warp (kg) reduction of PV partials via retired KV4 (f32 [64][64])
  float* red = (float*)KV4;
  if (kg == 1) {
#pragma unroll
    for (int qs = 0; qs < 2; ++qs)
#pragma unroll
      for (int ds = 0; ds < 4; ++ds)
#pragma unroll
        for (int r2 = 0; r2 < 4; ++r2)
          red[(qg * 32 + qs * 16 + l4 * 4 + r2) * 64 + ds * 16 + l15] = c[qs][ds][r2];
  }
  __syncthreads();
  if (kg == 0) {
    int b = bh >> 4, h = bh & 15;
#pragma unroll
    for (int qs = 0; qs < 2; ++qs)
#pragma unroll
      for (int ds = 0; ds < 4; ++ds)
#pragma unroll
        for (int r2 = 0; r2 < 4; ++r2) {
          int qr = qg * 32 + qs * 16 + l4 * 4 + r2;
          float v = c[qs][ds][r2] + red[qr * 64 + ds * 16 + l15];
          int s = qt * 64 + qr, d = ds * 16 + l15;
          ctx[((size_t)(b * SQ + s)) * DM + h * DK + d] = f2bf(v);
        }
  }
}

extern "C" void kernel_launch(void* const* d_in, const int* in_sizes, int n_in,
                              void* d_out, int out_size, void* d_ws, size_t ws_size,
                              hipStream_t stream)
{
  const float* x  = (const float*)d_in[0];
  const float* Wq = (const float*)d_in[1];
  const float* bq = (const float*)d_in[2];
  const float* Wk = (const float*)d_in[3];
  const float* bk = (const float*)d_in[4];
  const float* Wv = (const float*)d_in[5];
  const float* bv = (const float*)d_in[6];
  const float* Wo = (const float*)d_in[7];
  const float* bo = (const float*)d_in[8];

  char* p = (char*)d_ws;
  float2* rope = (float2*)p;  p += (size_t)SQ * 32 * sizeof(float2);
  short* xb  = (short*)p;     p += (size_t)4096 * DM * 2;
  short* Wqt = (short*)p;     p += (size_t)DM * DM * 2;
  short* Wkt = (short*)p;     p += (size_t)DM * DM * 2;
  short* Wvt = (short*)p;     p += (size_t)DM * DM * 2;
  short* Wot = (short*)p;     p += (size_t)DM * DM * 2;
  short* Qr  = (short*)p;     p += (size_t)2 * HD * SQ * DK * 2;
  short* Kr  = (short*)p;     p += (size_t)2 * HD * SQ * DK * 2;
  short* Vtr = (short*)p;     p += (size_t)2 * HD * SQ * DK * 2;
  short* ctx = (short*)p;     p += (size_t)4096 * DM * 2;

  k_prep<<<8448, 256, 0, stream>>>(x, xb, Wq, Wk, Wv, Wo, Wqt, Wkt, Wvt, Wot, rope);
  k_projqkv<<<dim3(32, 24), 256, 0, stream>>>(xb, Wqt, Wkt, Wvt, bq, bk, bv, rope, Qr, Kr, Vtr);
  float* attn = (float*)d_out + (size_t)2 * SQ * DM;
  k_attn2<<<1024, 256, 0, stream>>>(Qr, Kr, Vtr, attn, ctx);
  k_projO<<<dim3(64, 8), 256, 0, stream>>>(ctx, Wot, bo, (float*)d_out);
}